// Round 3
// baseline (104.117 us; speedup 1.0000x reference)
//
#include <hip/hip_runtime.h>
#include <hip/hip_bf16.h>
#include <stdint.h>

typedef short bf16x8 __attribute__((ext_vector_type(8)));
typedef unsigned short u16x8 __attribute__((ext_vector_type(8)));
typedef float f32x4 __attribute__((ext_vector_type(4)));

__device__ inline unsigned short f2bf(float f) {
    union { float f; uint32_t u; } v; v.f = f;
    uint32_t lsb = (v.u >> 16) & 1u;
    v.u += 0x7fffu + lsb;                // round-to-nearest-even
    return (unsigned short)(v.u >> 16);
}

// async 16B global -> LDS (dest = wave-uniform base + lane*16)
__device__ inline void gload16(const unsigned short* g, unsigned short* l) {
    __builtin_amdgcn_global_load_lds(
        (const __attribute__((address_space(1))) unsigned int*)g,
        (__attribute__((address_space(3))) unsigned int*)l, 16, 0, 0);
}

// ---------------- elementwise f32 -> bf16 (8 per thread)
__global__ __launch_bounds__(256) void cast_f32_bf16(const float* __restrict__ in,
                                                     unsigned short* __restrict__ out, int n8) {
    int i = blockIdx.x * 256 + threadIdx.x;
    if (i >= n8) return;
    const float4* p = (const float4*)in + (size_t)i * 2;
    float4 a = p[0], b = p[1];
    u16x8 o;
    o[0] = f2bf(a.x); o[1] = f2bf(a.y); o[2] = f2bf(a.z); o[3] = f2bf(a.w);
    o[4] = f2bf(b.x); o[5] = f2bf(b.y); o[6] = f2bf(b.z); o[7] = f2bf(b.w);
    *((u16x8*)out + i) = o;
}

// ---------------- [R][C] f32 -> [C][R] bf16 transpose (64x64 tiles)
__global__ __launch_bounds__(256) void transpose_cast(const float* __restrict__ in,
                                                      unsigned short* __restrict__ out,
                                                      int R, int C) {
    __shared__ float tile[64][65];
    const int t = threadIdx.x;
    const int r0 = blockIdx.y * 64, c0 = blockIdx.x * 64;
    {
        int r = t >> 2, cs = t & 3;
        #pragma unroll
        for (int i = 0; i < 4; ++i) {
            int c = (cs * 4 + i) * 4;
            float4 v = *(const float4*)(in + (size_t)(r0 + r) * C + c0 + c);
            tile[r][c] = v.x; tile[r][c + 1] = v.y; tile[r][c + 2] = v.z; tile[r][c + 3] = v.w;
        }
    }
    __syncthreads();
    {
        int c = t >> 2, rs = t & 3;
        #pragma unroll
        for (int i = 0; i < 2; ++i) {
            u16x8 o;
            #pragma unroll
            for (int e = 0; e < 8; ++e) o[e] = f2bf(tile[rs * 16 + i * 8 + e][c]);
            *(u16x8*)(out + (size_t)(c0 + c) * R + r0 + rs * 16 + i * 8) = o;
        }
    }
}

// ---------------- per-head V transpose: vT[h][d][j] = qkv[j][1536 + h*64 + d]
__global__ __launch_bounds__(256) void transpose_v(const unsigned short* __restrict__ qkv,
                                                   unsigned short* __restrict__ vT) {
    __shared__ unsigned short t[64][72];
    const int h = blockIdx.y;
    const int j0 = blockIdx.x * 64;
    const int tid = threadIdx.x;
    {
        int j = tid >> 2, s = tid & 3;
        const unsigned short* src = qkv + (size_t)(j0 + j) * 2304 + 1536 + h * 64;
        *(u16x8*)(&t[j][s * 8]) = *(const u16x8*)(src + s * 8);
        *(u16x8*)(&t[j][(s + 4) * 8]) = *(const u16x8*)(src + (s + 4) * 8);
    }
    __syncthreads();
    {
        int d = tid >> 2, s = tid & 3;
        #pragma unroll
        for (int i = 0; i < 2; ++i) {
            u16x8 o;
            #pragma unroll
            for (int e = 0; e < 8; ++e) o[e] = t[s * 16 + i * 8 + e][d];
            *(u16x8*)(vT + ((size_t)h * 64 + d) * 4096 + j0 + s * 16 + i * 8) = o;
        }
    }
}

// ---------------- bf16 MFMA GEMM (m97 structure): C = A[M,K] @ BT[N,K]^T + bias
// 128x128 tile, BK=64, 4 waves, global_load_lds width-16 staging, linear LDS.
template <int OUT_BF16>
__global__ __launch_bounds__(256) void gemm_bf16(const unsigned short* __restrict__ A,
                                                 const unsigned short* __restrict__ BT,
                                                 const float* __restrict__ bias,
                                                 void* __restrict__ Cout,
                                                 int M, int N, int K) {
    __shared__ unsigned short As[128 * 64];
    __shared__ unsigned short Bs[128 * 64];
    const int tid = threadIdx.x;
    const int lane = tid & 63;
    const int w = tid >> 6;
    const int wr = w >> 1, wc = w & 1;
    const int row0 = blockIdx.y * 128, col0 = blockIdx.x * 128;

    const int srow = lane >> 3;   // row within 8-row chunk
    const int sseg = lane & 7;    // 16B segment within 128B row

    f32x4 acc[4][4] = {};

    for (int k0 = 0; k0 < K; k0 += 64) {
        __syncthreads();   // previous iteration's fragment reads complete
        #pragma unroll
        for (int i = 0; i < 4; ++i) {
            const int ch = w * 4 + i;           // chunk 0..15 (8 rows each)
            const int r = ch * 8 + srow;
            gload16(A + (size_t)(row0 + r) * K + k0 + sseg * 8, As + ch * 512);
            gload16(BT + (size_t)(col0 + r) * K + k0 + sseg * 8, Bs + ch * 512);
        }
        __syncthreads();   // drains vmcnt -> LDS tiles ready
        bf16x8 af[2][4], bfr[2][4];
        #pragma unroll
        for (int m = 0; m < 4; ++m) {
            const int ra = (wr * 64 + m * 16 + (lane & 15)) * 64 + (lane >> 4) * 8;
            const int rb = (wc * 64 + m * 16 + (lane & 15)) * 64 + (lane >> 4) * 8;
            af[0][m]  = *(const bf16x8*)(As + ra);
            af[1][m]  = *(const bf16x8*)(As + ra + 32);
            bfr[0][m] = *(const bf16x8*)(Bs + rb);
            bfr[1][m] = *(const bf16x8*)(Bs + rb + 32);
        }
        #pragma unroll
        for (int ks = 0; ks < 2; ++ks)
            #pragma unroll
            for (int m = 0; m < 4; ++m)
                #pragma unroll
                for (int n = 0; n < 4; ++n)
                    acc[m][n] = __builtin_amdgcn_mfma_f32_16x16x32_bf16(af[ks][m], bfr[ks][n], acc[m][n], 0, 0, 0);
    }

    #pragma unroll
    for (int m = 0; m < 4; ++m) {
        int row = row0 + wr * 64 + m * 16 + (lane >> 4) * 4;
        #pragma unroll
        for (int n = 0; n < 4; ++n) {
            int col = col0 + wc * 64 + n * 16 + (lane & 15);
            float bb = bias[col];
            #pragma unroll
            for (int r = 0; r < 4; ++r) {
                float v = acc[m][n][r] + bb;
                if (OUT_BF16)
                    ((unsigned short*)Cout)[(size_t)(row + r) * N + col] = f2bf(v);
                else
                    ((float*)Cout)[(size_t)(row + r) * N + col] = v;
            }
        }
    }
}

// ---------------- flash-style sink+window attention, bf16 MFMA
// block: 64 queries x 1 head, 4 waves x 16 queries. Key tiles of 64.
__global__ __launch_bounds__(256) void attn_mfma(const unsigned short* __restrict__ qkv,
                                                 const unsigned short* __restrict__ vT,
                                                 unsigned short* __restrict__ ctx,
                                                 const int* __restrict__ pnsink,
                                                 const int* __restrict__ pwin) {
    __shared__ unsigned short Qs[64 * 72];
    __shared__ unsigned short Ks[64 * 72];
    __shared__ unsigned short Vt[64 * 72];
    __shared__ unsigned short Ps[64 * 72];
    const int tid = threadIdx.x, lane = tid & 63, w = tid >> 6;
    const int h = blockIdx.y;
    const int i0 = blockIdx.x * 64;
    const int nsink = *pnsink, wsize = *pwin;
    const int D3 = 2304;

    // stage Q block [64 rows][64 d] (pad-72 rows)
    {
        int q = tid >> 2, s1 = tid & 3;
        const unsigned short* src = qkv + (size_t)(i0 + q) * D3 + h * 64;
        *(u16x8*)(Qs + q * 72 + s1 * 8) = *(const u16x8*)(src + s1 * 8);
        *(u16x8*)(Qs + q * 72 + (s1 + 4) * 8) = *(const u16x8*)(src + (s1 + 4) * 8);
    }
    __syncthreads();
    // Q fragments are loop-invariant: hoist
    const bf16x8 aq0 = *(const bf16x8*)(Qs + (16 * w + (lane & 15)) * 72 + (lane >> 4) * 8);
    const bf16x8 aq1 = *(const bf16x8*)(Qs + (16 * w + (lane & 15)) * 72 + 32 + (lane >> 4) * 8);

    float mrow[4], lrow[4];
    f32x4 ctxacc[4];
    #pragma unroll
    for (int r = 0; r < 4; ++r) { mrow[r] = -1e30f; lrow[r] = 0.f; ctxacc[r] = (f32x4){0, 0, 0, 0}; }

    int wlo = i0 - wsize + 1; if (wlo < 0) wlo = 0;
    const int t_lo = (wlo >> 6) << 6;
    const int iq = i0 + 16 * w + ((lane >> 4) << 2);   // +r gives this lane's query rows
    const int ntiles = ((i0 - t_lo) >> 6) + 1 + (t_lo > 0 ? 1 : 0);

    for (int tt = 0; tt < ntiles; ++tt) {
        int kb;
        if (t_lo > 0) kb = (tt == 0) ? 0 : t_lo + ((tt - 1) << 6);
        else          kb = tt << 6;

        __syncthreads();
        // stage K rows [64][64] and V^T rows [d][j] (both pad-72, all vectorized)
        {
            int j = tid >> 2, s1 = tid & 3;
            const unsigned short* ksrc = qkv + (size_t)(kb + j) * D3 + 768 + h * 64;
            *(u16x8*)(Ks + j * 72 + s1 * 8) = *(const u16x8*)(ksrc + s1 * 8);
            *(u16x8*)(Ks + j * 72 + (s1 + 4) * 8) = *(const u16x8*)(ksrc + (s1 + 4) * 8);
            const unsigned short* vsrc = vT + ((size_t)h * 64 + j) * 4096 + kb;  // j is d here
            *(u16x8*)(Vt + j * 72 + s1 * 8) = *(const u16x8*)(vsrc + s1 * 8);
            *(u16x8*)(Vt + j * 72 + (s1 + 4) * 8) = *(const u16x8*)(vsrc + (s1 + 4) * 8);
        }
        __syncthreads();

        // QK^T: S[q 16][j 64] per wave
        f32x4 sacc[4];
        #pragma unroll
        for (int nb = 0; nb < 4; ++nb) {
            sacc[nb] = (f32x4){0, 0, 0, 0};
            bf16x8 bk0 = *(const bf16x8*)(Ks + (nb * 16 + (lane & 15)) * 72 + (lane >> 4) * 8);
            bf16x8 bk1 = *(const bf16x8*)(Ks + (nb * 16 + (lane & 15)) * 72 + 32 + (lane >> 4) * 8);
            sacc[nb] = __builtin_amdgcn_mfma_f32_16x16x32_bf16(aq0, bk0, sacc[nb], 0, 0, 0);
            sacc[nb] = __builtin_amdgcn_mfma_f32_16x16x32_bf16(aq1, bk1, sacc[nb], 0, 0, 0);
        }
        // mask + scale (C-frag: row q = (lane>>4)*4+r, col j = nb*16 + (lane&15))
        #pragma unroll
        for (int nb = 0; nb < 4; ++nb)
            #pragma unroll
            for (int r = 0; r < 4; ++r) {
                int iqr = iq + r;
                int j = kb + nb * 16 + (lane & 15);
                bool vis = (j <= iqr) && ((j < nsink) || (j > iqr - wsize));
                sacc[nb][r] = vis ? sacc[nb][r] * 0.125f : -1e30f;
            }
        // online softmax per row (16-lane row groups)
        float alpha[4];
        #pragma unroll
        for (int r = 0; r < 4; ++r) {
            float mt = fmaxf(fmaxf(sacc[0][r], sacc[1][r]), fmaxf(sacc[2][r], sacc[3][r]));
            mt = fmaxf(mt, __shfl_xor(mt, 1));
            mt = fmaxf(mt, __shfl_xor(mt, 2));
            mt = fmaxf(mt, __shfl_xor(mt, 4));
            mt = fmaxf(mt, __shfl_xor(mt, 8));
            float mn = fmaxf(mrow[r], mt);
            alpha[r] = __expf(mrow[r] - mn);
            mrow[r] = mn;
            bool dead = (mn <= -1e29f);   // no visible key yet for this row
            float rs = 0.f;
            #pragma unroll
            for (int nb = 0; nb < 4; ++nb) {
                float p = dead ? 0.f : __expf(sacc[nb][r] - mn);
                sacc[nb][r] = p;
                rs += p;
            }
            rs += __shfl_xor(rs, 1); rs += __shfl_xor(rs, 2);
            rs += __shfl_xor(rs, 4); rs += __shfl_xor(rs, 8);
            lrow[r] = lrow[r] * alpha[r] + rs;
        }
        // rescale ctx, write P (per-wave region rows 16w..16w+15)
        #pragma unroll
        for (int nb = 0; nb < 4; ++nb)
            #pragma unroll
            for (int r = 0; r < 4; ++r) ctxacc[nb][r] *= alpha[r];
        #pragma unroll
        for (int r = 0; r < 4; ++r)
            #pragma unroll
            for (int nb = 0; nb < 4; ++nb)
                Ps[(16 * w + (lane >> 4) * 4 + r) * 72 + nb * 16 + (lane & 15)] = f2bf(sacc[nb][r]);
        // PV: ctx[q 16][d 64] += P[16x64] @ V[64x64]  (wave-local Ps region, no barrier)
        bf16x8 pa0 = *(const bf16x8*)(Ps + (16 * w + (lane & 15)) * 72 + (lane >> 4) * 8);
        bf16x8 pa1 = *(const bf16x8*)(Ps + (16 * w + (lane & 15)) * 72 + 32 + (lane >> 4) * 8);
        #pragma unroll
        for (int nb = 0; nb < 4; ++nb) {
            bf16x8 bv0 = *(const bf16x8*)(Vt + (nb * 16 + (lane & 15)) * 72 + (lane >> 4) * 8);
            bf16x8 bv1 = *(const bf16x8*)(Vt + (nb * 16 + (lane & 15)) * 72 + 32 + (lane >> 4) * 8);
            ctxacc[nb] = __builtin_amdgcn_mfma_f32_16x16x32_bf16(pa0, bv0, ctxacc[nb], 0, 0, 0);
            ctxacc[nb] = __builtin_amdgcn_mfma_f32_16x16x32_bf16(pa1, bv1, ctxacc[nb], 0, 0, 0);
        }
    }

    // finalize: ctx/l -> bf16
    #pragma unroll
    for (int r = 0; r < 4; ++r) {
        float inv = 1.f / lrow[r];
        int row = i0 + 16 * w + ((lane >> 4) << 2) + r;
        #pragma unroll
        for (int nb = 0; nb < 4; ++nb)
            ctx[(size_t)row * 768 + h * 64 + nb * 16 + (lane & 15)] = f2bf(ctxacc[nb][r] * inv);
    }
}

extern "C" void kernel_launch(void* const* d_in, const int* in_sizes, int n_in,
                              void* d_out, int out_size, void* d_ws, size_t ws_size,
                              hipStream_t stream) {
    const float* x      = (const float*)d_in[0];
    const float* w_attn = (const float*)d_in[1];
    const float* b_attn = (const float*)d_in[2];
    const float* w_proj = (const float*)d_in[3];
    const float* b_proj = (const float*)d_in[4];
    const int*   pnsink = (const int*)d_in[5];
    const int*   pwin   = (const int*)d_in[6];
    float* out = (float*)d_out;

    const int D = 768, S = 4096, N1 = 3 * D;

    unsigned short* xbf   = (unsigned short*)d_ws;
    unsigned short* waT   = xbf + (size_t)S * D;
    unsigned short* wpT   = waT + (size_t)N1 * D;
    unsigned short* qkvbf = wpT + (size_t)D * D;
    unsigned short* ctxbf = qkvbf + (size_t)S * N1;
    unsigned short* vTbf  = ctxbf + (size_t)S * D;

    // prep: casts + weight transposes
    cast_f32_bf16<<<(S * D / 8 + 255) / 256, 256, 0, stream>>>(x, xbf, S * D / 8);
    {
        dim3 g(N1 / 64, D / 64);
        transpose_cast<<<g, 256, 0, stream>>>(w_attn, waT, D, N1);
    }
    {
        dim3 g(D / 64, D / 64);
        transpose_cast<<<g, 256, 0, stream>>>(w_proj, wpT, D, D);
    }
    // GEMM1: qkv = x @ w_attn + b_attn  -> bf16 [S, 3D]
    {
        dim3 g(N1 / 128, S / 128);
        gemm_bf16<1><<<g, 256, 0, stream>>>(xbf, waT, b_attn, qkvbf, S, N1, D);
    }
    // per-head V transpose
    {
        dim3 g(S / 64, 12);
        transpose_v<<<g, 256, 0, stream>>>(qkvbf, vTbf);
    }
    // attention -> ctx bf16 [S, D]
    {
        dim3 g(S / 64, 12);
        attn_mfma<<<g, 256, 0, stream>>>(qkvbf, vTbf, ctxbf, pnsink, pwin);
    }
    // GEMM2: out = ctx @ w_proj + b_proj -> f32
    {
        dim3 g(D / 128, S / 128);
        gemm_bf16<0><<<g, 256, 0, stream>>>(ctxbf, wpT, b_proj, out, S, D, D);
    }
}

// Round 4
// 86.716 us; speedup vs baseline: 1.2007x; 1.2007x over previous
//
#include <hip/hip_runtime.h>
#include <hip/hip_bf16.h>
#include <stdint.h>

typedef short bf16x8 __attribute__((ext_vector_type(8)));
typedef unsigned short u16x8 __attribute__((ext_vector_type(8)));
typedef float f32x4 __attribute__((ext_vector_type(4)));

__device__ inline unsigned short f2bf(float f) {
    union { float f; uint32_t u; } v; v.f = f;
    uint32_t lsb = (v.u >> 16) & 1u;
    v.u += 0x7fffu + lsb;                // round-to-nearest-even
    return (unsigned short)(v.u >> 16);
}

// async 16B global -> LDS (dest = wave-uniform base + lane*16)
__device__ inline void gload16(const unsigned short* g, unsigned short* l) {
    __builtin_amdgcn_global_load_lds(
        (const __attribute__((address_space(1))) unsigned int*)g,
        (__attribute__((address_space(3))) unsigned int*)l, 16, 0, 0);
}

// ---------------- elementwise f32 -> bf16 (8 per thread)
__global__ __launch_bounds__(256) void cast_f32_bf16(const float* __restrict__ in,
                                                     unsigned short* __restrict__ out, int n8) {
    int i = blockIdx.x * 256 + threadIdx.x;
    if (i >= n8) return;
    const float4* p = (const float4*)in + (size_t)i * 2;
    float4 a = p[0], b = p[1];
    u16x8 o;
    o[0] = f2bf(a.x); o[1] = f2bf(a.y); o[2] = f2bf(a.z); o[3] = f2bf(a.w);
    o[4] = f2bf(b.x); o[5] = f2bf(b.y); o[6] = f2bf(b.z); o[7] = f2bf(b.w);
    *((u16x8*)out + i) = o;
}

// ---------------- [R][C] f32 -> [C][R] bf16 transpose (64x64 tiles)
__global__ __launch_bounds__(256) void transpose_cast(const float* __restrict__ in,
                                                      unsigned short* __restrict__ out,
                                                      int R, int C) {
    __shared__ float tile[64][65];
    const int t = threadIdx.x;
    const int r0 = blockIdx.y * 64, c0 = blockIdx.x * 64;
    {
        int r = t >> 2, cs = t & 3;
        #pragma unroll
        for (int i = 0; i < 4; ++i) {
            int c = (cs * 4 + i) * 4;
            float4 v = *(const float4*)(in + (size_t)(r0 + r) * C + c0 + c);
            tile[r][c] = v.x; tile[r][c + 1] = v.y; tile[r][c + 2] = v.z; tile[r][c + 3] = v.w;
        }
    }
    __syncthreads();
    {
        int c = t >> 2, rs = t & 3;
        #pragma unroll
        for (int i = 0; i < 2; ++i) {
            u16x8 o;
            #pragma unroll
            for (int e = 0; e < 8; ++e) o[e] = f2bf(tile[rs * 16 + i * 8 + e][c]);
            *(u16x8*)(out + (size_t)(c0 + c) * R + r0 + rs * 16 + i * 8) = o;
        }
    }
}

// ---------------- per-head V transpose: vT[h][d][j] = qkv[j][1536 + h*64 + d]
__global__ __launch_bounds__(256) void transpose_v(const unsigned short* __restrict__ qkv,
                                                   unsigned short* __restrict__ vT) {
    __shared__ unsigned short t[64][72];
    const int h = blockIdx.y;
    const int j0 = blockIdx.x * 64;
    const int tid = threadIdx.x;
    {
        int j = tid >> 2, s = tid & 3;
        const unsigned short* src = qkv + (size_t)(j0 + j) * 2304 + 1536 + h * 64;
        *(u16x8*)(&t[j][s * 8]) = *(const u16x8*)(src + s * 8);
        *(u16x8*)(&t[j][(s + 4) * 8]) = *(const u16x8*)(src + (s + 4) * 8);
    }
    __syncthreads();
    {
        int d = tid >> 2, s = tid & 3;
        #pragma unroll
        for (int i = 0; i < 2; ++i) {
            u16x8 o;
            #pragma unroll
            for (int e = 0; e < 8; ++e) o[e] = t[s * 16 + i * 8 + e][d];
            *(u16x8*)(vT + ((size_t)h * 64 + d) * 4096 + j0 + s * 16 + i * 8) = o;
        }
    }
}

// ---------------- bf16 MFMA GEMM: C = A[M,K] @ BT[N,K]^T + bias
// 128x128 tile, BK=64, 4 waves, double-buffered LDS with global_load_lds
// staging (issue next tile before computing current), XOR bank swizzle
// (pre-swizzled global source + swizzled ds_read column; LDS stays linear).
template <int OUT_BF16>
__global__ __launch_bounds__(256) void gemm_bf16(const unsigned short* __restrict__ A,
                                                 const unsigned short* __restrict__ BT,
                                                 const float* __restrict__ bias,
                                                 void* __restrict__ Cout,
                                                 int M, int N, int K) {
    __shared__ unsigned short As[2][128 * 64];
    __shared__ unsigned short Bs[2][128 * 64];
    const int tid = threadIdx.x;
    const int lane = tid & 63;
    const int w = tid >> 6;
    const int wr = w >> 1, wc = w & 1;
    const int row0 = blockIdx.y * 128, col0 = blockIdx.x * 128;

    const int srow = lane >> 3;              // 0..7 row within 8-row chunk
    const int sseg = (lane & 7) ^ srow;      // swizzled source 16B segment

    const int nt = K >> 6;

    f32x4 acc[4][4] = {};

#define STAGE(buf, k0)                                                                     \
    {                                                                                      \
        _Pragma("unroll")                                                                  \
        for (int i = 0; i < 4; ++i) {                                                      \
            const int ch = w * 4 + i;                                                      \
            const int r = ch * 8 + srow;                                                   \
            gload16(A + (size_t)(row0 + r) * K + (k0) + sseg * 8, &As[buf][ch * 512]);     \
            gload16(BT + (size_t)(col0 + r) * K + (k0) + sseg * 8, &Bs[buf][ch * 512]);    \
        }                                                                                  \
    }

    STAGE(0, 0);
    int cur = 0;
    for (int t = 0; t < nt; ++t) {
        __syncthreads();   // drains vmcnt -> buf[cur] ready; prev-iter reads of buf[cur^1] done
        if (t + 1 < nt) {
            if (cur) STAGE(0, (t + 1) << 6) else STAGE(1, (t + 1) << 6);
        }
        const unsigned short* as = As[cur];
        const unsigned short* bs = Bs[cur];
        // swizzled read column (16B units): (ks*4 + lane>>4) ^ (row & 7); row&7 == lane&7
        const int c0s = ((0 + (lane >> 4)) ^ (lane & 7)) << 3;
        const int c1s = ((4 + (lane >> 4)) ^ (lane & 7)) << 3;
        bf16x8 af[2][4], bfr[2][4];
        #pragma unroll
        for (int m = 0; m < 4; ++m) {
            const int ra = (wr * 64 + m * 16 + (lane & 15)) * 64;
            const int rb = (wc * 64 + m * 16 + (lane & 15)) * 64;
            af[0][m]  = *(const bf16x8*)(as + ra + c0s);
            af[1][m]  = *(const bf16x8*)(as + ra + c1s);
            bfr[0][m] = *(const bf16x8*)(bs + rb + c0s);
            bfr[1][m] = *(const bf16x8*)(bs + rb + c1s);
        }
        #pragma unroll
        for (int ks = 0; ks < 2; ++ks)
            #pragma unroll
            for (int m = 0; m < 4; ++m)
                #pragma unroll
                for (int n = 0; n < 4; ++n)
                    acc[m][n] = __builtin_amdgcn_mfma_f32_16x16x32_bf16(af[ks][m], bfr[ks][n], acc[m][n], 0, 0, 0);
        cur ^= 1;
    }
#undef STAGE

    #pragma unroll
    for (int m = 0; m < 4; ++m) {
        int row = row0 + wr * 64 + m * 16 + (lane >> 4) * 4;
        #pragma unroll
        for (int n = 0; n < 4; ++n) {
            int col = col0 + wc * 64 + n * 16 + (lane & 15);
            float bb = bias[col];
            #pragma unroll
            for (int r = 0; r < 4; ++r) {
                float v = acc[m][n][r] + bb;
                if (OUT_BF16)
                    ((unsigned short*)Cout)[(size_t)(row + r) * N + col] = f2bf(v);
                else
                    ((float*)Cout)[(size_t)(row + r) * N + col] = v;
            }
        }
    }
}

// ---------------- flash-style sink+window attention, bf16 MFMA
// block: 64 queries x 1 head, 4 waves x 16 queries. Key tiles of 64.
__global__ __launch_bounds__(256) void attn_mfma(const unsigned short* __restrict__ qkv,
                                                 const unsigned short* __restrict__ vT,
                                                 unsigned short* __restrict__ ctx,
                                                 const int* __restrict__ pnsink,
                                                 const int* __restrict__ pwin) {
    __shared__ unsigned short Qs[64 * 72];
    __shared__ unsigned short Ks[64 * 72];
    __shared__ unsigned short Vt[64 * 72];
    __shared__ unsigned short Ps[64 * 72];
    const int tid = threadIdx.x, lane = tid & 63, w = tid >> 6;
    const int h = blockIdx.y;
    const int i0 = blockIdx.x * 64;
    const int nsink = *pnsink, wsize = *pwin;
    const int D3 = 2304;

    // stage Q block [64 rows][64 d] (pad-72 rows)
    {
        int q = tid >> 2, s1 = tid & 3;
        const unsigned short* src = qkv + (size_t)(i0 + q) * D3 + h * 64;
        *(u16x8*)(Qs + q * 72 + s1 * 8) = *(const u16x8*)(src + s1 * 8);
        *(u16x8*)(Qs + q * 72 + (s1 + 4) * 8) = *(const u16x8*)(src + (s1 + 4) * 8);
    }
    __syncthreads();
    // Q fragments are loop-invariant: hoist
    const bf16x8 aq0 = *(const bf16x8*)(Qs + (16 * w + (lane & 15)) * 72 + (lane >> 4) * 8);
    const bf16x8 aq1 = *(const bf16x8*)(Qs + (16 * w + (lane & 15)) * 72 + 32 + (lane >> 4) * 8);

    float mrow[4], lrow[4];
    f32x4 ctxacc[4];
    #pragma unroll
    for (int r = 0; r < 4; ++r) { mrow[r] = -1e30f; lrow[r] = 0.f; ctxacc[r] = (f32x4){0, 0, 0, 0}; }

    int wlo = i0 - wsize + 1; if (wlo < 0) wlo = 0;
    const int t_lo = (wlo >> 6) << 6;
    const int iq = i0 + 16 * w + ((lane >> 4) << 2);   // +r gives this lane's query rows
    const int ntiles = ((i0 - t_lo) >> 6) + 1 + (t_lo > 0 ? 1 : 0);

    for (int tt = 0; tt < ntiles; ++tt) {
        int kb;
        if (t_lo > 0) kb = (tt == 0) ? 0 : t_lo + ((tt - 1) << 6);
        else          kb = tt << 6;

        __syncthreads();
        // stage K rows [64][64] and V^T rows [d][j] (both pad-72, all vectorized)
        {
            int j = tid >> 2, s1 = tid & 3;
            const unsigned short* ksrc = qkv + (size_t)(kb + j) * D3 + 768 + h * 64;
            *(u16x8*)(Ks + j * 72 + s1 * 8) = *(const u16x8*)(ksrc + s1 * 8);
            *(u16x8*)(Ks + j * 72 + (s1 + 4) * 8) = *(const u16x8*)(ksrc + (s1 + 4) * 8);
            const unsigned short* vsrc = vT + ((size_t)h * 64 + j) * 4096 + kb;  // j is d here
            *(u16x8*)(Vt + j * 72 + s1 * 8) = *(const u16x8*)(vsrc + s1 * 8);
            *(u16x8*)(Vt + j * 72 + (s1 + 4) * 8) = *(const u16x8*)(vsrc + (s1 + 4) * 8);
        }
        __syncthreads();

        // QK^T: S[q 16][j 64] per wave
        f32x4 sacc[4];
        #pragma unroll
        for (int nb = 0; nb < 4; ++nb) {
            sacc[nb] = (f32x4){0, 0, 0, 0};
            bf16x8 bk0 = *(const bf16x8*)(Ks + (nb * 16 + (lane & 15)) * 72 + (lane >> 4) * 8);
            bf16x8 bk1 = *(const bf16x8*)(Ks + (nb * 16 + (lane & 15)) * 72 + 32 + (lane >> 4) * 8);
            sacc[nb] = __builtin_amdgcn_mfma_f32_16x16x32_bf16(aq0, bk0, sacc[nb], 0, 0, 0);
            sacc[nb] = __builtin_amdgcn_mfma_f32_16x16x32_bf16(aq1, bk1, sacc[nb], 0, 0, 0);
        }
        // mask + scale (C-frag: row q = (lane>>4)*4+r, col j = nb*16 + (lane&15))
        #pragma unroll
        for (int nb = 0; nb < 4; ++nb)
            #pragma unroll
            for (int r = 0; r < 4; ++r) {
                int iqr = iq + r;
                int j = kb + nb * 16 + (lane & 15);
                bool vis = (j <= iqr) && ((j < nsink) || (j > iqr - wsize));
                sacc[nb][r] = vis ? sacc[nb][r] * 0.125f : -1e30f;
            }
        // online softmax per row (16-lane row groups)
        float alpha[4];
        #pragma unroll
        for (int r = 0; r < 4; ++r) {
            float mt = fmaxf(fmaxf(sacc[0][r], sacc[1][r]), fmaxf(sacc[2][r], sacc[3][r]));
            mt = fmaxf(mt, __shfl_xor(mt, 1));
            mt = fmaxf(mt, __shfl_xor(mt, 2));
            mt = fmaxf(mt, __shfl_xor(mt, 4));
            mt = fmaxf(mt, __shfl_xor(mt, 8));
            float mn = fmaxf(mrow[r], mt);
            alpha[r] = __expf(mrow[r] - mn);
            mrow[r] = mn;
            bool dead = (mn <= -1e29f);   // no visible key yet for this row
            float rs = 0.f;
            #pragma unroll
            for (int nb = 0; nb < 4; ++nb) {
                float p = dead ? 0.f : __expf(sacc[nb][r] - mn);
                sacc[nb][r] = p;
                rs += p;
            }
            rs += __shfl_xor(rs, 1); rs += __shfl_xor(rs, 2);
            rs += __shfl_xor(rs, 4); rs += __shfl_xor(rs, 8);
            lrow[r] = lrow[r] * alpha[r] + rs;
        }
        // rescale ctx, write P (per-wave region rows 16w..16w+15)
        #pragma unroll
        for (int nb = 0; nb < 4; ++nb)
            #pragma unroll
            for (int r = 0; r < 4; ++r) ctxacc[nb][r] *= alpha[r];
        #pragma unroll
        for (int r = 0; r < 4; ++r)
            #pragma unroll
            for (int nb = 0; nb < 4; ++nb)
                Ps[(16 * w + (lane >> 4) * 4 + r) * 72 + nb * 16 + (lane & 15)] = f2bf(sacc[nb][r]);
        // PV: ctx[q 16][d 64] += P[16x64] @ V[64x64]  (wave-local Ps region, no barrier)
        bf16x8 pa0 = *(const bf16x8*)(Ps + (16 * w + (lane & 15)) * 72 + (lane >> 4) * 8);
        bf16x8 pa1 = *(const bf16x8*)(Ps + (16 * w + (lane & 15)) * 72 + 32 + (lane >> 4) * 8);
        #pragma unroll
        for (int nb = 0; nb < 4; ++nb) {
            bf16x8 bv0 = *(const bf16x8*)(Vt + (nb * 16 + (lane & 15)) * 72 + (lane >> 4) * 8);
            bf16x8 bv1 = *(const bf16x8*)(Vt + (nb * 16 + (lane & 15)) * 72 + 32 + (lane >> 4) * 8);
            ctxacc[nb] = __builtin_amdgcn_mfma_f32_16x16x32_bf16(pa0, bv0, ctxacc[nb], 0, 0, 0);
            ctxacc[nb] = __builtin_amdgcn_mfma_f32_16x16x32_bf16(pa1, bv1, ctxacc[nb], 0, 0, 0);
        }
    }

    // finalize: ctx/l -> bf16
    #pragma unroll
    for (int r = 0; r < 4; ++r) {
        float inv = 1.f / lrow[r];
        int row = i0 + 16 * w + ((lane >> 4) << 2) + r;
        #pragma unroll
        for (int nb = 0; nb < 4; ++nb)
            ctx[(size_t)row * 768 + h * 64 + nb * 16 + (lane & 15)] = f2bf(ctxacc[nb][r] * inv);
    }
}

extern "C" void kernel_launch(void* const* d_in, const int* in_sizes, int n_in,
                              void* d_out, int out_size, void* d_ws, size_t ws_size,
                              hipStream_t stream) {
    const float* x      = (const float*)d_in[0];
    const float* w_attn = (const float*)d_in[1];
    const float* b_attn = (const float*)d_in[2];
    const float* w_proj = (const float*)d_in[3];
    const float* b_proj = (const float*)d_in[4];
    const int*   pnsink = (const int*)d_in[5];
    const int*   pwin   = (const int*)d_in[6];
    float* out = (float*)d_out;

    const int D = 768, S = 4096, N1 = 3 * D;

    unsigned short* xbf   = (unsigned short*)d_ws;
    unsigned short* waT   = xbf + (size_t)S * D;
    unsigned short* wpT   = waT + (size_t)N1 * D;
    unsigned short* qkvbf = wpT + (size_t)D * D;
    unsigned short* ctxbf = qkvbf + (size_t)S * N1;
    unsigned short* vTbf  = ctxbf + (size_t)S * D;

    // prep: casts + weight transposes
    cast_f32_bf16<<<(S * D / 8 + 255) / 256, 256, 0, stream>>>(x, xbf, S * D / 8);
    {
        dim3 g(N1 / 64, D / 64);
        transpose_cast<<<g, 256, 0, stream>>>(w_attn, waT, D, N1);
    }
    {
        dim3 g(D / 64, D / 64);
        transpose_cast<<<g, 256, 0, stream>>>(w_proj, wpT, D, D);
    }
    // GEMM1: qkv = x @ w_attn + b_attn  -> bf16 [S, 3D]
    {
        dim3 g(N1 / 128, S / 128);
        gemm_bf16<1><<<g, 256, 0, stream>>>(xbf, waT, b_attn, qkvbf, S, N1, D);
    }
    // per-head V transpose
    {
        dim3 g(S / 64, 12);
        transpose_v<<<g, 256, 0, stream>>>(qkvbf, vTbf);
    }
    // attention -> ctx bf16 [S, D]
    {
        dim3 g(S / 64, 12);
        attn_mfma<<<g, 256, 0, stream>>>(qkvbf, vTbf, ctxbf, pnsink, pwin);
    }
    // GEMM2: out = ctx @ w_proj + b_proj -> f32
    {
        dim3 g(D / 128, S / 128);
        gemm_bf16<0><<<g, 256, 0, stream>>>(ctxbf, wpT, b_proj, out, S, D, D);
    }
}